// Round 5
// baseline (338.990 us; speedup 1.0000x reference)
//
#include <hip/hip_runtime.h>
#include <hip/hip_bf16.h>

// B=2, S=2048, HID=2048, NH=16, HD=128.
// cast->bf16, QKV GEMM (3-buffer counted-vmcnt MFMA pipeline), rope tables,
// rope+rmsnorm (in-place), flash attention (balanced tile-pairing, swapped QK^T,
// sigma-permuted PV), projection GEMM (BM=128 variant, fp32 out).

typedef __attribute__((ext_vector_type(8))) short short8_t;   // 8 x bf16
typedef __attribute__((ext_vector_type(4))) short short4_t;
typedef __attribute__((ext_vector_type(4))) float f32x4;

#define S_LEN 2048
#define NHEAD 16
#define HDIM  128
#define HID   2048
#define MROWS 4096            // B*S
#define SCALEF 0.08838834764831845f

__device__ __forceinline__ float bf2f(ushort u) {
  union { unsigned int u; float f; } a; a.u = ((unsigned int)u) << 16; return a.f;
}
__device__ __forceinline__ ushort f2bf(float f) {
  union { float f; unsigned int u; } a; a.f = f;
  unsigned int r = a.u + 0x7FFFu + ((a.u >> 16) & 1u);
  return (ushort)(r >> 16);
}
__device__ __forceinline__ void store_out(ushort* p, float v) { *p = f2bf(v); }
__device__ __forceinline__ void store_out(float* p, float v) { *p = v; }

// async global->LDS, 16B per lane; LDS dest must be wave-uniform (HW adds lane*16).
__device__ __forceinline__ void gload_lds16(const void* g, void* l) {
  __builtin_amdgcn_global_load_lds(
      (const __attribute__((address_space(1))) unsigned int*)g,
      (__attribute__((address_space(3))) unsigned int*)l, 16, 0, 0);
}

// ---------------------------------------------------------------- casts
__global__ __launch_bounds__(256) void cast_bf16_kernel(
    const float* __restrict__ in, ushort* __restrict__ out, int n4) {
  int i = blockIdx.x * 256 + threadIdx.x;
  const int stride = gridDim.x * 256;
  for (; i < n4; i += stride) {
    float4 v = ((const float4*)in)[i];
    short4_t o = { (short)f2bf(v.x), (short)f2bf(v.y),
                   (short)f2bf(v.z), (short)f2bf(v.w) };
    ((short4_t*)out)[i] = o;
  }
}

// ---------------------------------------------------------------- rope tables
__global__ __launch_bounds__(256) void rope_tab_kernel(
    float* __restrict__ cosT, float* __restrict__ sinT) {
  int idx = blockIdx.x * 256 + threadIdx.x;
  if (idx >= S_LEN * 64) return;
  int s = idx >> 6, i = idx & 63;
  float f = expf(9.2103403719761836f * (float)(2 * i));
  float inv = 1.0f / f;                 // inf -> 0, matches reference
  float ang = (float)s * inv;
  cosT[idx] = cosf(ang);
  sinT[idx] = sinf(ang);
}

// ---------------------------------------------------------------- pipelined GEMM
// C = A @ W^T. Tile: BM = MH*128 x BN = 256, BK = 32. 8 waves (2m x 4n).
// 3 LDS buffers; tile T lives in buf T%3; stages for T+2 -> buf (T+2)%3.
// Per-wave counted vmcnt: drain own T+1 stages (vmcnt(MH+2... see below))
// BEFORE the end-of-tile barrier => after barrier, ALL waves' next-tile data
// is resident. Stage units/tile: A = MH gloads, B = 2 gloads (per thread).
// LDS rows are 64B with XOR swizzle slot = chunk ^ (row&3); the inverse is
// applied to the per-lane GLOBAL source column (rule 21: linear LDS dest).
#define RD_BF() _Pragma("unroll") for (int j = 0; j < 4; ++j) { \
    const int rw = wn * 64 + j * 16 + lq; \
    bfr[j] = *(const short8_t*)(bufp + ABYTES + rw * 64 + ((lg ^ (rw & 3)) << 4)); }
#define RD_AF(P) _Pragma("unroll") for (int i = 0; i < 4; ++i) { \
    const int rw = wm * (MH * 64) + (P) * 64 + i * 16 + lq; \
    af[i] = *(const short8_t*)(bufp + rw * 64 + ((lg ^ (rw & 3)) << 4)); }
#define MFMA_Q(P) _Pragma("unroll") for (int i = 0; i < 4; ++i) \
    _Pragma("unroll") for (int j = 0; j < 4; ++j) \
      acc[(P) * 4 + i][j] = __builtin_amdgcn_mfma_f32_16x16x32_bf16( \
          af[i], bfr[j], acc[(P) * 4 + i][j], 0, 0, 0);
#define STG_A(BI, KC) { gload_lds16(pa0 + (KC), lds + (BI) * BUF + wb); \
    if constexpr (MH == 2) gload_lds16(pa1 + (KC), lds + (BI) * BUF + 8192 + wb); }
#define STG_B(BI, KC) { gload_lds16(pw0 + (KC), lds + (BI) * BUF + ABYTES + wb); \
    gload_lds16(pw1 + (KC), lds + (BI) * BUF + ABYTES + 8192 + wb); }
#define WAIT_OWN_NEXT() \
    if (st) { if constexpr (MH == 2) asm volatile("s_waitcnt vmcnt(4)" ::: "memory"); \
              else                   asm volatile("s_waitcnt vmcnt(3)" ::: "memory"); } \
    else     asm volatile("s_waitcnt vmcnt(0)" ::: "memory");
#define MID_SYNC() \
    __builtin_amdgcn_s_barrier(); \
    asm volatile("s_waitcnt lgkmcnt(0)" ::: "memory"); \
    __builtin_amdgcn_sched_barrier(0); \
    __builtin_amdgcn_s_setprio(1);

template <int MH, typename OutT>
__global__ __launch_bounds__(512, 2) void gemm_pipe_kernel(
    const ushort* __restrict__ A, const ushort* __restrict__ W,
    OutT* __restrict__ C, int M, int N, int K) {
  constexpr int ABYTES = MH * 8192;       // A bytes per buffer
  constexpr int BUF = ABYTES + 16384;     // buffer stride (A + B)
  __shared__ __align__(16) char lds[3 * BUF];

  const int n0 = blockIdx.x * 256;
  const int m0 = blockIdx.y * (MH * 128);
  const ushort* Wz = W + (size_t)blockIdx.z * N * K;
  OutT* Cz = C + (size_t)blockIdx.z * M * N;

  const int tid = threadIdx.x;
  const int lane = tid & 63, wid = tid >> 6;
  const int lq = lane & 15, lg = lane >> 4;
  const int wm = wid >> 2, wn = wid & 3;
  const int NT = K >> 5;                  // BK = 32
  const int wb = wid * 1024;              // wave-uniform LDS byte base

  // staging thread geometry: thread writes LDS row tid>>2, slot tid&3;
  // source column chunk = (tid&3) ^ (row&3)  (inverse of the read swizzle).
  const int sr = tid >> 2;                // 0..127
  const int sc = ((tid & 3) ^ (sr & 3)) * 8;
  const ushort* pa0 = A + (size_t)(m0 + sr) * K + sc;
  const ushort* pa1 = A + (size_t)(m0 + 128 + sr) * K + sc;   // MH==2 only
  const ushort* pw0 = Wz + (size_t)(n0 + sr) * K + sc;
  const ushort* pw1 = Wz + (size_t)(n0 + 128 + sr) * K + sc;

  f32x4 acc[MH * 4][4];
#pragma unroll
  for (int i = 0; i < MH * 4; i++)
#pragma unroll
    for (int j = 0; j < 4; j++) acc[i][j] = (f32x4){0.f, 0.f, 0.f, 0.f};

  // prologue: stage tiles 0 and 1; drain own tile-0 loads; barrier.
  STG_A(0, 0); STG_B(0, 0);
  STG_A(1, 32); STG_B(1, 32);
  if constexpr (MH == 2) asm volatile("s_waitcnt vmcnt(4)" ::: "memory");
  else                   asm volatile("s_waitcnt vmcnt(3)" ::: "memory");
  __builtin_amdgcn_s_barrier();
  __builtin_amdgcn_sched_barrier(0);

  int b = 0, b2 = 2;                      // t%3 and (t+2)%3
  for (int t = 0; t < NT; ++t) {
    const int kc2 = (t + 2) << 5;
    const bool st = (t + 2 < NT);
    const char* bufp = lds + b * BUF;
    short8_t af[4], bfr[4];

    // phase 0: B frags + A m-half 0; stage T+2.A
    RD_BF(); RD_AF(0);
    if (st) { STG_A(b2, kc2); if constexpr (MH == 1) STG_B(b2, kc2); }
    MID_SYNC();
    MFMA_Q(0);
    __builtin_amdgcn_s_setprio(0);

    if constexpr (MH == 2) {
      __builtin_amdgcn_s_barrier();       // end phase 0
      __builtin_amdgcn_sched_barrier(0);
      // phase 1: A m-half 1; stage T+2.B
      RD_AF(1);
      if (st) STG_B(b2, kc2);
      MID_SYNC();
      MFMA_Q(1);
      __builtin_amdgcn_s_setprio(0);
    }

    // end of tile: each wave drains its OWN tile-T+1 stages, then barrier
    // => after barrier all waves' T+1 data is resident in buf (T+1)%3.
    WAIT_OWN_NEXT();
    __builtin_amdgcn_s_barrier();
    __builtin_amdgcn_sched_barrier(0);
    b = (b == 2) ? 0 : b + 1;
    b2 = (b2 == 2) ? 0 : b2 + 1;
  }

#pragma unroll
  for (int mi = 0; mi < MH * 4; mi++) {
#pragma unroll
    for (int r = 0; r < 4; r++) {
      const int m = m0 + wm * (MH * 64) + (mi >> 2) * 64 + (mi & 3) * 16 + lg * 4 + r;
      OutT* cp = Cz + (size_t)m * N + n0 + wn * 64 + lq;
#pragma unroll
      for (int j = 0; j < 4; j++) store_out(cp + j * 16, acc[mi][j][r]);
    }
  }
}

// ---------------------------------------------------------------- RoPE + RMSNorm
__global__ __launch_bounds__(256) void rope_norm_kernel(
    const ushort* __restrict__ in, ushort* __restrict__ out,
    const float* __restrict__ nw, const float* __restrict__ cosT,
    const float* __restrict__ sinT) {
  const int w = threadIdx.x >> 6, lane = threadIdx.x & 63;
  const int rid = blockIdx.x * 4 + w;          // (b*S+s)*NH + h
  const int s = (rid >> 4) & (S_LEN - 1);
  const size_t off = (size_t)rid * HDIM;
  float x1 = bf2f(in[off + lane]);
  float x2 = bf2f(in[off + 64 + lane]);
  float c = cosT[s * 64 + lane], sn = sinT[s * 64 + lane];
  float y1 = x1 * c - x2 * sn;
  float y2 = x2 * c + x1 * sn;
  float ss = y1 * y1 + y2 * y2;
#pragma unroll
  for (int m = 1; m < 64; m <<= 1) ss += __shfl_xor(ss, m, 64);
  float sc = rsqrtf(ss * (1.f / 128.f) + 1e-6f);
  out[off + lane] = f2bf(y1 * sc * nw[lane]);
  out[off + 64 + lane] = f2bf(y2 * sc * nw[lane + 64]);
}

// ---------------------------------------------------------------- flash attention
// Grid = 512 blocks: (b, h, j) with j=0..15; each block runs q-tiles {j, 31-j}.
// 4 waves x 16 q-rows per tile. Swapped QK^T; P stays in registers via
// sigma-permuted V columns (packed k-pairs as uint).
__global__ __launch_bounds__(256) void attn_kernel(
    const ushort* __restrict__ Q, const ushort* __restrict__ K,
    const ushort* __restrict__ V, ushort* __restrict__ O) {
  __shared__ __align__(16) ushort Ks[32 * 128];    // XOR-swizzled rows (256B)
  __shared__ __align__(16) uint Vt32[128 * 18];    // [d][pair-col], pad 18

  const int bid = blockIdx.x;
  const int jj = bid & 15;
  const int h  = (bid >> 4) & 15;
  const int b  = bid >> 8;
  const int tid = threadIdx.x;
  const int lane = tid & 63, w = tid >> 6;
  const int lq = lane & 15, lg = lane >> 4;

  const int krow0 = w * 8 + (lane >> 4);
  const int krow1 = krow0 + 4;
  const int kc0 = ((lane & 15) * 16) ^ ((krow0 & 7) << 4);
  const int kc1 = ((lane & 15) * 16) ^ ((krow1 & 7) << 4);
  const int vp  = tid & 15;
  const int vd0 = (tid >> 4) * 8;
  const int vc  = (vp < 8) ? ((vp >> 1) * 4 + (vp & 1))
                           : (((vp - 8) >> 1) * 4 + 2 + (vp & 1));

  for (int t = 0; t < 2; t++) {
    const int qt = t ? (31 - jj) : jj;
    const int q0 = qt * 64 + w * 16;

    const ushort* qp = Q + (size_t)(b * S_LEN + q0 + lq) * HID + h * HDIM + lg * 8;
    short8_t qf[4];
#pragma unroll
    for (int dc = 0; dc < 4; dc++) qf[dc] = *(const short8_t*)(qp + dc * 32);

    f32x4 o[8];
#pragma unroll
    for (int i = 0; i < 8; i++) o[i] = (f32x4){0.f, 0.f, 0.f, 0.f};
    float m_run = -1e30f, l_run = 0.f;
    const int qlim = q0 + 15;
    const int kmax = qt * 64 + 64;

    for (int k0 = 0; k0 < kmax; k0 += 32) {
      __syncthreads();
      {
        const size_t kbase = (size_t)(b * S_LEN + k0) * HID + h * HDIM;
        gload_lds16(K + kbase + (size_t)krow0 * HID + (kc0 >> 1),
                    (char*)Ks + w * 2048);
        gload_lds16(K + kbase + (size_t)krow1 * HID + (kc1 >> 1),
                    (char*)Ks + w * 2048 + 1024);
        const ushort* vsrc = V + kbase + (size_t)(2 * vp) * HID + vd0;
        short8_t va = *(const short8_t*)vsrc;
        short8_t vb = *(const short8_t*)(vsrc + HID);
#pragma unroll
        for (int e = 0; e < 8; e++)
          Vt32[(vd0 + e) * 18 + vc] =
              (uint)(ushort)va[e] | ((uint)(ushort)vb[e] << 16);
      }
      __syncthreads();
      if (k0 > qlim) continue;

      f32x4 st0 = (f32x4){0.f, 0.f, 0.f, 0.f};
      f32x4 st1 = (f32x4){0.f, 0.f, 0.f, 0.f};
      const char* ksb = (const char*)Ks;
#pragma unroll
      for (int dc = 0; dc < 4; dc++) {
        const int row0 = lq, row1 = 16 + lq;
        short8_t kf0 = *(const short8_t*)(ksb + ((row0 * 256 + dc * 64 + lg * 16) ^ ((row0 & 7) << 4)));
        short8_t kf1 = *(const short8_t*)(ksb + ((row1 * 256 + dc * 64 + lg * 16) ^ ((row1 & 7) << 4)));
        st0 = __builtin_amdgcn_mfma_f32_16x16x32_bf16(kf0, qf[dc], st0, 0, 0, 0);
        st1 = __builtin_amdgcn_mfma_f32_16x16x32_bf16(kf1, qf[dc], st1, 0, 0, 0);
      }

      const int qg = q0 + lq;
      float sv[8]; float mx = -1e30f;
#pragma unroll
      for (int r = 0; r < 4; r++) {
        const int kk0 = k0 + lg * 4 + r;
        const int kk1 = kk0 + 16;
        float v0 = (kk0 <= qg) ? st0[r] * SCALEF : -1e30f;
        float v1 = (kk1 <= qg) ? st1[r] * SCALEF : -1e30f;
        sv[r] = v0; sv[4 + r] = v1;
        mx = fmaxf(mx, fmaxf(v0, v1));
      }
      mx = fmaxf(mx, __shfl_xor(mx, 16, 64));
      mx = fmaxf(mx, __shfl_xor(mx, 32, 64));
      const float m_new = fmaxf(m_run, mx);
      const float alpha = __expf(m_run - m_new);
      float p[8]; float ps = 0.f;
#pragma unroll
      for (int i = 0; i < 8; i++) { p[i] = __expf(sv[i] - m_new); ps += p[i]; }
      ps += __shfl_xor(ps, 16, 64);
      ps += __shfl_xor(ps, 32, 64);
      l_run = l_run * alpha + ps;
      m_run = m_new;
#pragma unroll
      for (int r = 0; r < 4; r++) {
        const float ar = __shfl(alpha, lg * 4 + r, 64);
#pragma unroll
        for (int nt = 0; nt < 8; nt++) o[nt][r] *= ar;
      }

      union { uint u[4]; short8_t s; } pu;
      pu.u[0] = (uint)f2bf(p[0]) | ((uint)f2bf(p[1]) << 16);
      pu.u[1] = (uint)f2bf(p[2]) | ((uint)f2bf(p[3]) << 16);
      pu.u[2] = (uint)f2bf(p[4]) | ((uint)f2bf(p[5]) << 16);
      pu.u[3] = (uint)f2bf(p[6]) | ((uint)f2bf(p[7]) << 16);
      const short8_t pa = pu.s;

#pragma unroll
      for (int nt = 0; nt < 8; nt++) {
        const uint* vq = &Vt32[(nt * 16 + lq) * 18 + lg * 4];
        uint2 vlo = *(const uint2*)vq;
        uint2 vhi = *(const uint2*)(vq + 2);
        union { uint u[4]; short8_t s; } vu;
        vu.u[0] = vlo.x; vu.u[1] = vlo.y; vu.u[2] = vhi.x; vu.u[3] = vhi.y;
        o[nt] = __builtin_amdgcn_mfma_f32_16x16x32_bf16(pa, vu.s, o[nt], 0, 0, 0);
      }
    }

    const float invl = (l_run > 0.f) ? 1.f / l_run : 0.f;
#pragma unroll
    for (int r = 0; r < 4; r++) {
      const float iv = __shfl(invl, lg * 4 + r, 64);
      ushort* op = O + (size_t)(b * S_LEN + q0 + lg * 4 + r) * HID + h * HDIM + lq;
#pragma unroll
      for (int nt = 0; nt < 8; nt++) op[nt * 16] = f2bf(o[nt][r] * iv);
    }
  }
}

// ---------------------------------------------------------------- launcher
extern "C" void kernel_launch(void* const* d_in, const int* in_sizes, int n_in,
                              void* d_out, int out_size, void* d_ws, size_t ws_size,
                              hipStream_t stream) {
  const float* x   = (const float*)d_in[0];
  const float* wq  = (const float*)d_in[1];
  const float* wk  = (const float*)d_in[2];
  const float* wv  = (const float*)d_in[3];
  const float* wo  = (const float*)d_in[4];
  const float* qnw = (const float*)d_in[5];
  const float* knw = (const float*)d_in[6];
  float* out = (float*)d_out;
  char* ws = (char*)d_ws;

  const size_t NELEM = (size_t)MROWS * HID;       // 8388608
  const size_t WELEM = (size_t)HID * HID;         // 4194304

  ushort* xb    = (ushort*)(ws);                          // 16777216 B
  ushort* wqkvb = (ushort*)(ws + 16777216);               // 25165824 B
  ushort* wob   = (ushort*)(ws + 41943040);               //  8388608 B
  ushort* qkv   = (ushort*)(ws + 50331648);               // 50331648 B (q,k,v)
  float*  cosT  = (float*)(ws + 100663296);               //   524288 B
  float*  sinT  = (float*)(ws + 101187584);               //   524288 B
  ushort* attnb = xb;                                     // alias (xb dead after QKV)

  cast_bf16_kernel<<<1024, 256, 0, stream>>>(x, xb, (int)(NELEM / 4));
  cast_bf16_kernel<<<1024, 256, 0, stream>>>(wq, wqkvb, (int)(WELEM / 4));
  cast_bf16_kernel<<<1024, 256, 0, stream>>>(wk, wqkvb + WELEM, (int)(WELEM / 4));
  cast_bf16_kernel<<<1024, 256, 0, stream>>>(wv, wqkvb + 2 * WELEM, (int)(WELEM / 4));
  cast_bf16_kernel<<<1024, 256, 0, stream>>>(wo, wob, (int)(WELEM / 4));
  rope_tab_kernel<<<512, 256, 0, stream>>>(cosT, sinT);

  // QKV = x @ {wq,wk,wv}^T (bf16 out): BM=256 x BN=256, 384 blocks
  gemm_pipe_kernel<2, ushort><<<dim3(8, 16, 3), 512, 0, stream>>>(
      xb, wqkvb, qkv, MROWS, HID, HID);

  rope_norm_kernel<<<16384, 256, 0, stream>>>(qkv, qkv, qnw, cosT, sinT);
  rope_norm_kernel<<<16384, 256, 0, stream>>>(qkv + NELEM, qkv + NELEM, knw, cosT, sinT);

  attn_kernel<<<512, 256, 0, stream>>>(qkv, qkv + NELEM, qkv + 2 * NELEM, attnb);

  // out = attn @ wo^T (fp32 out): BM=128 x BN=256, 256 blocks (full CU coverage)
  gemm_pipe_kernel<1, float><<<dim3(8, 32, 1), 512, 0, stream>>>(
      attnb, wob, out, MROWS, HID, HID);
}

// Round 6
// 322.862 us; speedup vs baseline: 1.0500x; 1.0500x over previous
//
#include <hip/hip_runtime.h>
#include <hip/hip_bf16.h>

// B=2, S=2048, HID=2048, NH=16, HD=128.
// cast->bf16, QKV GEMM (BM256xBN128xBK64, 3-buffer depth-2 counted-vmcnt
// pipeline, conflict-free XOR swizzle), rope tables, rope+rmsnorm (in-place),
// flash attention (balanced tile-pairing, swapped QK^T, sigma-permuted PV),
// projection GEMM (same kernel, fp32 out). Grids are exact multiples of 256 CUs.

typedef __attribute__((ext_vector_type(8))) short short8_t;   // 8 x bf16
typedef __attribute__((ext_vector_type(4))) short short4_t;
typedef __attribute__((ext_vector_type(4))) float f32x4;

#define S_LEN 2048
#define NHEAD 16
#define HDIM  128
#define HID   2048
#define MROWS 4096            // B*S
#define SCALEF 0.08838834764831845f

__device__ __forceinline__ float bf2f(ushort u) {
  union { unsigned int u; float f; } a; a.u = ((unsigned int)u) << 16; return a.f;
}
__device__ __forceinline__ ushort f2bf(float f) {
  union { float f; unsigned int u; } a; a.f = f;
  unsigned int r = a.u + 0x7FFFu + ((a.u >> 16) & 1u);
  return (ushort)(r >> 16);
}
__device__ __forceinline__ void store_out(ushort* p, float v) { *p = f2bf(v); }
__device__ __forceinline__ void store_out(float* p, float v) { *p = v; }

// async global->LDS, 16B per lane; LDS dest must be wave-uniform (HW adds lane*16).
__device__ __forceinline__ void gload_lds16(const void* g, void* l) {
  __builtin_amdgcn_global_load_lds(
      (const __attribute__((address_space(1))) unsigned int*)g,
      (__attribute__((address_space(3))) unsigned int*)l, 16, 0, 0);
}

// ---------------------------------------------------------------- casts
__global__ __launch_bounds__(256) void cast_bf16_kernel(
    const float* __restrict__ in, ushort* __restrict__ out, int n4) {
  int i = blockIdx.x * 256 + threadIdx.x;
  const int stride = gridDim.x * 256;
  for (; i < n4; i += stride) {
    float4 v = ((const float4*)in)[i];
    short4_t o = { (short)f2bf(v.x), (short)f2bf(v.y),
                   (short)f2bf(v.z), (short)f2bf(v.w) };
    ((short4_t*)out)[i] = o;
  }
}

// ---------------------------------------------------------------- rope tables
__global__ __launch_bounds__(256) void rope_tab_kernel(
    float* __restrict__ cosT, float* __restrict__ sinT) {
  int idx = blockIdx.x * 256 + threadIdx.x;
  if (idx >= S_LEN * 64) return;
  int s = idx >> 6, i = idx & 63;
  float f = expf(9.2103403719761836f * (float)(2 * i));
  float inv = 1.0f / f;                 // inf -> 0, matches reference
  float ang = (float)s * inv;
  cosT[idx] = cosf(ang);
  sinT[idx] = sinf(ang);
}

// ---------------------------------------------------------------- pipelined GEMM
// C = A @ W^T. BM=256 x BN=128, BK=64. 8 waves (4m x 2n), 512 threads.
// Wave C = 64x64 (acc[4][4]); 16 MFMA per k-step, 2 phases per K-tile.
// LDS: 3 buffers x (A 32KB + B 16KB) = 144KB. Tile T in buf T%3; stages for
// T+2 -> buf (T+2)%3 issued during T (3 gloads per phase, 6/tile/thread).
// Boundary: s_waitcnt vmcnt(6) -> T+1 resident, T+2's 6 loads stay in flight
// (~2 tiles of MFMA cover). Rows are 128B, 8 slots of 16B; swizzle
// slot_phys = kchunk ^ (row&7) (bank = 4*slot mod 32 -> 16 lanes land 2/bank
// group = conflict-free, verified 0 conflicts in round 4). global_load_lds
// writes linear, so the INVERSE swizzle is applied to the per-lane global
// source column (rule 21).
#define RD_FRAGS(KK) \
  _Pragma("unroll") for (int j = 0; j < 4; ++j) { \
    const int rw = wn * 64 + j * 16 + lq; \
    bfr[j] = *(const short8_t*)(bufp + ABYTES + rw * 128 + \
                                ((((KK) * 4 + lg) ^ (rw & 7)) << 4)); } \
  _Pragma("unroll") for (int i = 0; i < 4; ++i) { \
    const int rw = wm * 64 + i * 16 + lq; \
    af[i] = *(const short8_t*)(bufp + rw * 128 + \
                               ((((KK) * 4 + lg) ^ (rw & 7)) << 4)); }
#define MFMA_ALL() _Pragma("unroll") for (int i = 0; i < 4; ++i) \
    _Pragma("unroll") for (int j = 0; j < 4; ++j) \
      acc[i][j] = __builtin_amdgcn_mfma_f32_16x16x32_bf16( \
          af[i], bfr[j], acc[i][j], 0, 0, 0);
#define MID_SYNC() \
    __builtin_amdgcn_s_barrier(); \
    asm volatile("s_waitcnt lgkmcnt(0)" ::: "memory"); \
    __builtin_amdgcn_sched_barrier(0); \
    __builtin_amdgcn_s_setprio(1);
#define END_PHASE() \
    __builtin_amdgcn_s_setprio(0);

template <typename OutT>
__global__ __launch_bounds__(512, 2) void gemm_pipe_kernel(
    const ushort* __restrict__ A, const ushort* __restrict__ W,
    OutT* __restrict__ C, int M, int N, int K) {
  constexpr int ABYTES = 32768;           // A bytes per buffer (256 x 128B)
  constexpr int BUF = 49152;              // A + B (128 x 128B)
  __shared__ __align__(16) char lds[3 * BUF];   // 147456 B

  const int n0 = blockIdx.x * 128;
  const int m0 = blockIdx.y * 256;
  const ushort* Wz = W + (size_t)blockIdx.z * N * K;
  OutT* Cz = C + (size_t)blockIdx.z * M * N;

  const int tid = threadIdx.x;
  const int lane = tid & 63, wid = tid >> 6;
  const int lq = lane & 15, lg = lane >> 4;
  const int wm = wid >> 1, wn = wid & 1;
  const int NT = K >> 6;                  // BK = 64
  const int wb = wid * 1024;              // wave-uniform LDS byte base per call

  // staging: per gload call, thread covers row strow (of 64), slot tid&7;
  // global source k-chunk = (tid&7) ^ (strow&7)  (inverse of read swizzle).
  const int strow = tid >> 3;             // 0..63
  const int sc8 = (((tid & 7) ^ (strow & 7)) << 3);   // element col 0..56
  const ushort* pa = A + (size_t)(m0 + strow) * K + sc8;
  const ushort* pw = Wz + (size_t)(n0 + strow) * K + sc8;

#define STG_P0(BI, KC) { \
    gload_lds16(pa + (KC), lds + (BI) * BUF + wb); \
    gload_lds16(pa + (size_t)64 * K + (KC), lds + (BI) * BUF + 8192 + wb); \
    gload_lds16(pw + (KC), lds + (BI) * BUF + ABYTES + wb); }
#define STG_P1(BI, KC) { \
    gload_lds16(pa + (size_t)128 * K + (KC), lds + (BI) * BUF + 16384 + wb); \
    gload_lds16(pa + (size_t)192 * K + (KC), lds + (BI) * BUF + 24576 + wb); \
    gload_lds16(pw + (size_t)64 * K + (KC), lds + (BI) * BUF + ABYTES + 8192 + wb); }

  f32x4 acc[4][4];
#pragma unroll
  for (int i = 0; i < 4; i++)
#pragma unroll
    for (int j = 0; j < 4; j++) acc[i][j] = (f32x4){0.f, 0.f, 0.f, 0.f};

  // prologue: stage tiles 0 and 1 (6 loads each); drain tile 0; barrier.
  STG_P0(0, 0); STG_P1(0, 0);
  STG_P0(1, 64); STG_P1(1, 64);
  asm volatile("s_waitcnt vmcnt(6)" ::: "memory");
  __builtin_amdgcn_s_barrier();
  __builtin_amdgcn_sched_barrier(0);

  int b = 0, b2 = 2;                      // t%3 and (t+2)%3
  for (int t = 0; t < NT; ++t) {
    const int kc2 = (t + 2) << 6;
    const bool st = (t + 2 < NT);
    const char* bufp = lds + b * BUF;
    short8_t af[4], bfr[4];

    // phase 0 (k-step 0): read frags; stage half of T+2
    RD_FRAGS(0);
    if (st) STG_P0(b2, kc2);
    MID_SYNC();
    MFMA_ALL();
    END_PHASE();
    __builtin_amdgcn_s_barrier();
    __builtin_amdgcn_sched_barrier(0);

    // phase 1 (k-step 1): read frags; stage other half of T+2
    RD_FRAGS(1);
    if (st) STG_P1(b2, kc2);
    MID_SYNC();
    MFMA_ALL();
    END_PHASE();
    // boundary: drain to 6 outstanding -> T+1 fully resident, T+2 in flight.
    if (st) asm volatile("s_waitcnt vmcnt(6)" ::: "memory");
    else    asm volatile("s_waitcnt vmcnt(0)" ::: "memory");
    __builtin_amdgcn_s_barrier();
    __builtin_amdgcn_sched_barrier(0);
    b = (b == 2) ? 0 : b + 1;
    b2 = (b2 == 2) ? 0 : b2 + 1;
  }

#pragma unroll
  for (int mi = 0; mi < 4; mi++) {
#pragma unroll
    for (int r = 0; r < 4; r++) {
      const int m = m0 + wm * 64 + mi * 16 + lg * 4 + r;
      OutT* cp = Cz + (size_t)m * N + n0 + wn * 64 + lq;
#pragma unroll
      for (int j = 0; j < 4; j++) store_out(cp + j * 16, acc[mi][j][r]);
    }
  }
}

// ---------------------------------------------------------------- RoPE + RMSNorm
__global__ __launch_bounds__(256) void rope_norm_kernel(
    const ushort* __restrict__ in, ushort* __restrict__ out,
    const float* __restrict__ nw, const float* __restrict__ cosT,
    const float* __restrict__ sinT) {
  const int w = threadIdx.x >> 6, lane = threadIdx.x & 63;
  const int rid = blockIdx.x * 4 + w;          // (b*S+s)*NH + h
  const int s = (rid >> 4) & (S_LEN - 1);
  const size_t off = (size_t)rid * HDIM;
  float x1 = bf2f(in[off + lane]);
  float x2 = bf2f(in[off + 64 + lane]);
  float c = cosT[s * 64 + lane], sn = sinT[s * 64 + lane];
  float y1 = x1 * c - x2 * sn;
  float y2 = x2 * c + x1 * sn;
  float ss = y1 * y1 + y2 * y2;
#pragma unroll
  for (int m = 1; m < 64; m <<= 1) ss += __shfl_xor(ss, m, 64);
  float sc = rsqrtf(ss * (1.f / 128.f) + 1e-6f);
  out[off + lane] = f2bf(y1 * sc * nw[lane]);
  out[off + 64 + lane] = f2bf(y2 * sc * nw[lane + 64]);
}

// ---------------------------------------------------------------- flash attention
// Grid = 512 blocks: (b, h, j) with j=0..15; each block runs q-tiles {j, 31-j}.
// 4 waves x 16 q-rows per tile. Swapped QK^T; P stays in registers via
// sigma-permuted V columns (packed k-pairs as uint).
__global__ __launch_bounds__(256) void attn_kernel(
    const ushort* __restrict__ Q, const ushort* __restrict__ K,
    const ushort* __restrict__ V, ushort* __restrict__ O) {
  __shared__ __align__(16) ushort Ks[32 * 128];    // XOR-swizzled rows (256B)
  __shared__ __align__(16) uint Vt32[128 * 18];    // [d][pair-col], pad 18

  const int bid = blockIdx.x;
  const int jj = bid & 15;
  const int h  = (bid >> 4) & 15;
  const int b  = bid >> 8;
  const int tid = threadIdx.x;
  const int lane = tid & 63, w = tid >> 6;
  const int lq = lane & 15, lg = lane >> 4;

  const int krow0 = w * 8 + (lane >> 4);
  const int krow1 = krow0 + 4;
  const int kc0 = ((lane & 15) * 16) ^ ((krow0 & 7) << 4);
  const int kc1 = ((lane & 15) * 16) ^ ((krow1 & 7) << 4);
  const int vp  = tid & 15;
  const int vd0 = (tid >> 4) * 8;
  const int vc  = (vp < 8) ? ((vp >> 1) * 4 + (vp & 1))
                           : (((vp - 8) >> 1) * 4 + 2 + (vp & 1));

  for (int t = 0; t < 2; t++) {
    const int qt = t ? (31 - jj) : jj;
    const int q0 = qt * 64 + w * 16;

    const ushort* qp = Q + (size_t)(b * S_LEN + q0 + lq) * HID + h * HDIM + lg * 8;
    short8_t qf[4];
#pragma unroll
    for (int dc = 0; dc < 4; dc++) qf[dc] = *(const short8_t*)(qp + dc * 32);

    f32x4 o[8];
#pragma unroll
    for (int i = 0; i < 8; i++) o[i] = (f32x4){0.f, 0.f, 0.f, 0.f};
    float m_run = -1e30f, l_run = 0.f;
    const int qlim = q0 + 15;
    const int kmax = qt * 64 + 64;

    for (int k0 = 0; k0 < kmax; k0 += 32) {
      __syncthreads();
      {
        const size_t kbase = (size_t)(b * S_LEN + k0) * HID + h * HDIM;
        gload_lds16(K + kbase + (size_t)krow0 * HID + (kc0 >> 1),
                    (char*)Ks + w * 2048);
        gload_lds16(K + kbase + (size_t)krow1 * HID + (kc1 >> 1),
                    (char*)Ks + w * 2048 + 1024);
        const ushort* vsrc = V + kbase + (size_t)(2 * vp) * HID + vd0;
        short8_t va = *(const short8_t*)vsrc;
        short8_t vb = *(const short8_t*)(vsrc + HID);
#pragma unroll
        for (int e = 0; e < 8; e++)
          Vt32[(vd0 + e) * 18 + vc] =
              (uint)(ushort)va[e] | ((uint)(ushort)vb[e] << 16);
      }
      __syncthreads();
      if (k0 > qlim) continue;

      f32x4 st0 = (f32x4){0.f, 0.f, 0.f, 0.f};
      f32x4 st1 = (f32x4){0.f, 0.f, 0.f, 0.f};
      const char* ksb = (const char*)Ks;
#pragma unroll
      for (int dc = 0; dc < 4; dc++) {
        const int row0 = lq, row1 = 16 + lq;
        short8_t kf0 = *(const short8_t*)(ksb + ((row0 * 256 + dc * 64 + lg * 16) ^ ((row0 & 7) << 4)));
        short8_t kf1 = *(const short8_t*)(ksb + ((row1 * 256 + dc * 64 + lg * 16) ^ ((row1 & 7) << 4)));
        st0 = __builtin_amdgcn_mfma_f32_16x16x32_bf16(kf0, qf[dc], st0, 0, 0, 0);
        st1 = __builtin_amdgcn_mfma_f32_16x16x32_bf16(kf1, qf[dc], st1, 0, 0, 0);
      }

      const int qg = q0 + lq;
      float sv[8]; float mx = -1e30f;
#pragma unroll
      for (int r = 0; r < 4; r++) {
        const int kk0 = k0 + lg * 4 + r;
        const int kk1 = kk0 + 16;
        float v0 = (kk0 <= qg) ? st0[r] * SCALEF : -1e30f;
        float v1 = (kk1 <= qg) ? st1[r] * SCALEF : -1e30f;
        sv[r] = v0; sv[4 + r] = v1;
        mx = fmaxf(mx, fmaxf(v0, v1));
      }
      mx = fmaxf(mx, __shfl_xor(mx, 16, 64));
      mx = fmaxf(mx, __shfl_xor(mx, 32, 64));
      const float m_new = fmaxf(m_run, mx);
      const float alpha = __expf(m_run - m_new);
      float p[8]; float ps = 0.f;
#pragma unroll
      for (int i = 0; i < 8; i++) { p[i] = __expf(sv[i] - m_new); ps += p[i]; }
      ps += __shfl_xor(ps, 16, 64);
      ps += __shfl_xor(ps, 32, 64);
      l_run = l_run * alpha + ps;
      m_run = m_new;
#pragma unroll
      for (int r = 0; r < 4; r++) {
        const float ar = __shfl(alpha, lg * 4 + r, 64);
#pragma unroll
        for (int nt = 0; nt < 8; nt++) o[nt][r] *= ar;
      }

      union { uint u[4]; short8_t s; } pu;
      pu.u[0] = (uint)f2bf(p[0]) | ((uint)f2bf(p[1]) << 16);
      pu.u[1] = (uint)f2bf(p[2]) | ((uint)f2bf(p[3]) << 16);
      pu.u[2] = (uint)f2bf(p[4]) | ((uint)f2bf(p[5]) << 16);
      pu.u[3] = (uint)f2bf(p[6]) | ((uint)f2bf(p[7]) << 16);
      const short8_t pa = pu.s;

#pragma unroll
      for (int nt = 0; nt < 8; nt++) {
        const uint* vq = &Vt32[(nt * 16 + lq) * 18 + lg * 4];
        uint2 vlo = *(const uint2*)vq;
        uint2 vhi = *(const uint2*)(vq + 2);
        union { uint u[4]; short8_t s; } vu;
        vu.u[0] = vlo.x; vu.u[1] = vlo.y; vu.u[2] = vhi.x; vu.u[3] = vhi.y;
        o[nt] = __builtin_amdgcn_mfma_f32_16x16x32_bf16(pa, vu.s, o[nt], 0, 0, 0);
      }
    }

    const float invl = (l_run > 0.f) ? 1.f / l_run : 0.f;
#pragma unroll
    for (int r = 0; r < 4; r++) {
      const float iv = __shfl(invl, lg * 4 + r, 64);
      ushort* op = O + (size_t)(b * S_LEN + q0 + lg * 4 + r) * HID + h * HDIM + lq;
#pragma unroll
      for (int nt = 0; nt < 8; nt++) op[nt * 16] = f2bf(o[nt][r] * iv);
    }
  }
}

// ---------------------------------------------------------------- launcher
extern "C" void kernel_launch(void* const* d_in, const int* in_sizes, int n_in,
                              void* d_out, int out_size, void* d_ws, size_t ws_size,
                              hipStream_t stream) {
  const float* x   = (const float*)d_in[0];
  const float* wq  = (const float*)d_in[1];
  const float* wk  = (const float*)d_in[2];
  const float* wv  = (const float*)d_in[3];
  const float* wo  = (const float*)d_in[4];
  const float* qnw = (const float*)d_in[5];
  const float* knw = (const float*)d_in[6];
  float* out = (float*)d_out;
  char* ws = (char*)d_ws;

  const size_t NELEM = (size_t)MROWS * HID;       // 8388608
  const size_t WELEM = (size_t)HID * HID;         // 4194304

  ushort* xb    = (ushort*)(ws);                          // 16777216 B
  ushort* wqkvb = (ushort*)(ws + 16777216);               // 25165824 B
  ushort* wob   = (ushort*)(ws + 41943040);               //  8388608 B
  ushort* qkv   = (ushort*)(ws + 50331648);               // 50331648 B (q,k,v)
  float*  cosT  = (float*)(ws + 100663296);               //   524288 B
  float*  sinT  = (float*)(ws + 101187584);               //   524288 B
  ushort* attnb = xb;                                     // alias (xb dead after QKV)

  cast_bf16_kernel<<<1024, 256, 0, stream>>>(x, xb, (int)(NELEM / 4));
  cast_bf16_kernel<<<1024, 256, 0, stream>>>(wq, wqkvb, (int)(WELEM / 4));
  cast_bf16_kernel<<<1024, 256, 0, stream>>>(wk, wqkvb + WELEM, (int)(WELEM / 4));
  cast_bf16_kernel<<<1024, 256, 0, stream>>>(wv, wqkvb + 2 * WELEM, (int)(WELEM / 4));
  cast_bf16_kernel<<<1024, 256, 0, stream>>>(wo, wob, (int)(WELEM / 4));
  rope_tab_kernel<<<512, 256, 0, stream>>>(cosT, sinT);

  // QKV = x @ {wq,wk,wv}^T (bf16 out): BM=256 x BN=128, 768 blocks = 3x256 CUs
  gemm_pipe_kernel<ushort><<<dim3(16, 16, 3), 512, 0, stream>>>(
      xb, wqkvb, qkv, MROWS, HID, HID);

  rope_norm_kernel<<<16384, 256, 0, stream>>>(qkv, qkv, qnw, cosT, sinT);
  rope_norm_kernel<<<16384, 256, 0, stream>>>(qkv + NELEM, qkv + NELEM, knw, cosT, sinT);

  attn_kernel<<<512, 256, 0, stream>>>(qkv, qkv + NELEM, qkv + 2 * NELEM, attnb);

  // out = attn @ wo^T (fp32 out): 256 blocks = 1x256 CUs
  gemm_pipe_kernel<float><<<dim3(16, 16, 1), 512, 0, stream>>>(
      attnb, wob, out, MROWS, HID, HID);
}